// Round 2
// baseline (577.466 us; speedup 1.0000x reference)
//
#include <hip/hip_runtime.h>
#include <math.h>

typedef unsigned short ushort_t;
typedef __attribute__((ext_vector_type(4))) float floatx4;
typedef __attribute__((ext_vector_type(8))) short bf16x8;

#define DIMC 1152
#define NHEADS 16
#define HDIM 72

__device__ __forceinline__ ushort_t f2bf(float f) {
  unsigned u = __float_as_uint(f);
  u += 0x7FFFu + ((u >> 16) & 1u);      // round-to-nearest-even
  return (ushort_t)(u >> 16);
}
__device__ __forceinline__ float bf2f(ushort_t s) {
  return __uint_as_float(((unsigned)s) << 16);
}

// ---------------------------------------------------------------------------
// W [K][N] fp32  ->  Wt [N][K] bf16   (64x64 tiles via LDS)
// ---------------------------------------------------------------------------
__global__ void transpose_w_kernel(const float* __restrict__ W,
                                   ushort_t* __restrict__ Wt, int K, int N) {
  __shared__ ushort_t tile[64 * 80];
  int k0 = blockIdx.x * 64, n0 = blockIdx.y * 64;
  int tid = threadIdx.x;
  int kl = tid >> 4, n4 = tid & 15;
  for (int rr = 0; rr < 4; rr++) {
    int k = kl + rr * 16;
    float4 f = *(const float4*)(W + (size_t)(k0 + k) * N + n0 + n4 * 4);
    tile[(n4 * 4 + 0) * 80 + k] = f2bf(f.x);
    tile[(n4 * 4 + 1) * 80 + k] = f2bf(f.y);
    tile[(n4 * 4 + 2) * 80 + k] = f2bf(f.z);
    tile[(n4 * 4 + 3) * 80 + k] = f2bf(f.w);
  }
  __syncthreads();
  // each thread writes 16 contiguous bf16 (= 2 x uint4): 64 rows x 4 threads
  int nl = tid >> 2, kq = tid & 3;
  uint4 v0 = *(const uint4*)(tile + nl * 80 + kq * 16);
  uint4 v1 = *(const uint4*)(tile + nl * 80 + kq * 16 + 8);
  *(uint4*)(Wt + (size_t)(n0 + nl) * K + k0 + kq * 16) = v0;
  *(uint4*)(Wt + (size_t)(n0 + nl) * K + k0 + kq * 16 + 8) = v1;
}

// ---------------------------------------------------------------------------
// C[M][N] = A[M][K] @ Wt[N][K]^T + bias.  A fp32 or bf16; C fp32 or bf16.
// 128x128 tile, BK=64, 256 threads (4 waves 2x2, each 64x64 = 4x4 frags).
// ---------------------------------------------------------------------------
#define LDT 88

template <bool A_F32, bool OUT_F32>
__global__ __launch_bounds__(256, 3) void gemm_kernel(
    const void* __restrict__ Aptr, const ushort_t* __restrict__ Bt,
    const float* __restrict__ bias, void* __restrict__ Cptr,
    int Mrows, int Ncols, int Kdim) {
  __shared__ ushort_t As[128 * LDT];
  __shared__ ushort_t Bs[128 * LDT];
  int tid = threadIdx.x;
  int m0 = blockIdx.y * 128, n0 = blockIdx.x * 128;
  int wid = tid >> 6, lane = tid & 63, quad = lane >> 4, l16 = lane & 15;
  int wrow = (wid >> 1) * 64, wcol = (wid & 1) * 64;
  int srow = tid >> 1, shalf = tid & 1;

  floatx4 zero = {0.f, 0.f, 0.f, 0.f};
  floatx4 acc[4][4];
  for (int i = 0; i < 4; i++)
    for (int j = 0; j < 4; j++) acc[i][j] = zero;

  int nK = Kdim >> 6;
  for (int kt = 0; kt < nK; kt++) {
    int k0 = kt * 64;
    __syncthreads();
    // stage A: each thread 32 contiguous bf16 of one row-half
    ushort_t* ad = As + srow * LDT + shalf * 32;
    if constexpr (A_F32) {
      const float* as = (const float*)Aptr + (size_t)(m0 + srow) * Kdim + k0 + shalf * 32;
      for (int i = 0; i < 4; i++) {
        float4 f0 = *(const float4*)(as + i * 8);
        float4 f1 = *(const float4*)(as + i * 8 + 4);
        union { ushort_t s[8]; uint4 u; } t;
        t.s[0] = f2bf(f0.x); t.s[1] = f2bf(f0.y); t.s[2] = f2bf(f0.z); t.s[3] = f2bf(f0.w);
        t.s[4] = f2bf(f1.x); t.s[5] = f2bf(f1.y); t.s[6] = f2bf(f1.z); t.s[7] = f2bf(f1.w);
        *(uint4*)(ad + i * 8) = t.u;
      }
    } else {
      const ushort_t* as = (const ushort_t*)Aptr + (size_t)(m0 + srow) * Kdim + k0 + shalf * 32;
      for (int i = 0; i < 4; i++) *(uint4*)(ad + i * 8) = *(const uint4*)(as + i * 8);
    }
    // stage B (always bf16 [N][K])
    {
      const ushort_t* bs = Bt + (size_t)(n0 + srow) * Kdim + k0 + shalf * 32;
      ushort_t* bd = Bs + srow * LDT + shalf * 32;
      for (int i = 0; i < 4; i++) *(uint4*)(bd + i * 8) = *(const uint4*)(bs + i * 8);
    }
    __syncthreads();
    for (int ks = 0; ks < 2; ks++) {
      bf16x8 af[4], bfr[4];
      for (int rb = 0; rb < 4; rb++)
        af[rb] = *(const bf16x8*)(As + (wrow + rb * 16 + l16) * LDT + ks * 32 + quad * 8);
      for (int c = 0; c < 4; c++)
        bfr[c] = *(const bf16x8*)(Bs + (wcol + c * 16 + l16) * LDT + ks * 32 + quad * 8);
      for (int rb = 0; rb < 4; rb++)
        for (int c = 0; c < 4; c++)
          acc[rb][c] = __builtin_amdgcn_mfma_f32_16x16x32_bf16(af[rb], bfr[c], acc[rb][c], 0, 0, 0);
    }
  }

  float bv[4];
  for (int c = 0; c < 4; c++) bv[c] = bias[n0 + wcol + c * 16 + l16];
  for (int rb = 0; rb < 4; rb++)
    for (int c = 0; c < 4; c++)
      for (int r = 0; r < 4; r++) {
        int row = m0 + wrow + rb * 16 + quad * 4 + r;
        int col = n0 + wcol + c * 16 + l16;
        float v = acc[rb][c][r] + bv[c];
        if constexpr (OUT_F32)
          ((float*)Cptr)[(size_t)row * Ncols + col] = v;
        else
          ((ushort_t*)Cptr)[(size_t)row * Ncols + col] = f2bf(v);
      }
}

// ---------------------------------------------------------------------------
// In-place per-head RMSNorm on bf16 (one wave per (row, head); 72 elems).
// ---------------------------------------------------------------------------
__global__ void rmsnorm_heads_kernel(ushort_t* __restrict__ p,
                                     const float* __restrict__ w,
                                     int rowstride) {
  int gw = blockIdx.x * 4 + (threadIdx.x >> 6);
  int lane = threadIdx.x & 63;
  int row = gw >> 4, h = gw & 15;
  ushort_t* base = p + (size_t)row * rowstride + h * HDIM;
  float v0 = bf2f(base[lane]);
  float v1 = (lane < 8) ? bf2f(base[64 + lane]) : 0.f;
  float ss = v0 * v0 + v1 * v1;
  for (int off = 1; off < 64; off <<= 1) ss += __shfl_xor(ss, off);
  float inv = rsqrtf(ss / 72.0f + 1e-6f);
  base[lane] = f2bf(v0 * inv * w[lane]);
  if (lane < 8) base[64 + lane] = f2bf(v1 * inv * w[64 + lane]);
}

// ---------------------------------------------------------------------------
// V [b,m,pair1,h,d] -> vT [b,h,d(80,zero-pad),m(512)]   (one wave per (b,h,d))
// ---------------------------------------------------------------------------
__global__ void vtrans_kernel(const ushort_t* __restrict__ kv16,
                              ushort_t* __restrict__ vT) {
  int gw = blockIdx.x * 4 + (threadIdx.x >> 6);
  int lane = threadIdx.x & 63;
  int d = gw % 80;
  int bh = gw / 80;
  int b = bh >> 4, h = bh & 15;
  ushort_t* dst = vT + (size_t)gw * 512;
  if (d < HDIM) {
    const ushort_t* src = kv16 + (size_t)b * 512 * 2304 + DIMC + h * HDIM + d;
    for (int m = lane; m < 512; m += 64) dst[m] = src[(size_t)m * 2304];
  } else {
    for (int m = lane; m < 512; m += 64) dst[m] = 0;
  }
}

// ---------------------------------------------------------------------------
// Flash cross-attention. Block = (b, h, 128 Q rows); 4 waves x 32 rows.
// M-tiles of 64. D padded to 96 (QK: Q frags masked to zero past 72, K
// staged with zero pad) / 80 (PV, zeros in vT).
// ---------------------------------------------------------------------------
__global__ __launch_bounds__(256, 3) void attn_kernel(
    const ushort_t* __restrict__ q16, const ushort_t* __restrict__ kv16,
    const ushort_t* __restrict__ vT, const int* __restrict__ seqlens,
    ushort_t* __restrict__ att) {
  __shared__ ushort_t Ks[64 * 104];   // [m 64][d 96, stride 104]
  __shared__ ushort_t Vs[80 * 72];    // [d 80][m 64, stride 72]
  __shared__ ushort_t Ps[128 * 72];   // [qrow 128][m 64, stride 72]
  int b = blockIdx.z, h = blockIdx.y, n0 = blockIdx.x * 128;
  int tid = threadIdx.x, wid = tid >> 6, lane = tid & 63;
  int quad = lane >> 4, l16 = lane & 15;
  int seqlen = seqlens[b];
  const float scale = 0.11785113019775793f;  // 1/sqrt(72)

  // Q fragments (A-operand). k >= 72 explicitly zeroed (quad-uniform branch).
  bf16x8 qf[2][3];
  for (int rb = 0; rb < 2; rb++)
    for (int ks = 0; ks < 3; ks++) {
      if (ks == 2 && quad > 0) {
        qf[rb][ks] = (bf16x8){0, 0, 0, 0, 0, 0, 0, 0};
      } else {
        size_t off = ((size_t)(b * 4096 + n0 + wid * 32 + rb * 16 + l16)) * DIMC +
                     h * HDIM + ks * 32 + quad * 8;
        union { bf16x8 v; uint2 u[2]; } t;
        t.u[0] = *(const uint2*)(q16 + off);
        t.u[1] = *(const uint2*)(q16 + off + 4);
        qf[rb][ks] = t.v;
      }
    }

  floatx4 zero = {0.f, 0.f, 0.f, 0.f};
  floatx4 of[2][5];
  floatx4 m_run[2], l_run[2];
  for (int rb = 0; rb < 2; rb++) {
    for (int nf = 0; nf < 5; nf++) of[rb][nf] = zero;
    m_run[rb] = (floatx4){-INFINITY, -INFINITY, -INFINITY, -INFINITY};
    l_run[rb] = zero;
  }

  int ntiles = (seqlen + 63) >> 6;
  for (int mt = 0; mt < ntiles; mt++) {
    int m0 = mt * 64;
    __syncthreads();
    // stage K tile: 64 rows x 96 cols; each (r,seg) covers 24 bf16 = 3 uint4
    {
      int r = tid >> 2, seg = tid & 3;
      const ushort_t* src = kv16 + ((size_t)(b * 512 + m0 + r)) * 2304 + h * HDIM + seg * 24;
      ushort_t* dst = Ks + r * 104 + seg * 24;
      if (seg < 3) {
        for (int i = 0; i < 3; i++) *(uint4*)(dst + i * 8) = *(const uint4*)(src + i * 8);
      } else {
        uint4 z = make_uint4(0u, 0u, 0u, 0u);
        for (int i = 0; i < 3; i++) *(uint4*)(dst + i * 8) = z;
      }
    }
    // stage V tile
    for (int c = tid; c < 640; c += 256) {
      int d = c >> 3, j = c & 7;
      *(uint4*)(Vs + d * 72 + j * 8) =
          *(const uint4*)(vT + ((size_t)((b * 16 + h) * 80 + d)) * 512 + m0 + j * 8);
    }
    __syncthreads();

    // S = Q K^T
    floatx4 sf[2][4];
    for (int rb = 0; rb < 2; rb++)
      for (int c = 0; c < 4; c++) sf[rb][c] = zero;
    for (int c = 0; c < 4; c++)
      for (int ks = 0; ks < 3; ks++) {
        bf16x8 kf = *(const bf16x8*)(Ks + (c * 16 + l16) * 104 + ks * 32 + quad * 8);
        for (int rb = 0; rb < 2; rb++)
          sf[rb][c] = __builtin_amdgcn_mfma_f32_16x16x32_bf16(qf[rb][ks], kf, sf[rb][c], 0, 0, 0);
      }

    // online softmax per rb (rows quad*4+r; stats reduced over 16 lanes)
    for (int rb = 0; rb < 2; rb++) {
      float pv[4][4], alpha[4];
      for (int r = 0; r < 4; r++) {
        float mx = -INFINITY;
        for (int c = 0; c < 4; c++) {
          int col = m0 + c * 16 + l16;
          float s = sf[rb][c][r] * scale;
          if (col < seqlen && s > mx) mx = s;
        }
        for (int off = 1; off < 16; off <<= 1) {
          float o = __shfl_xor(mx, off);
          if (o > mx) mx = o;
        }
        float mold = m_run[rb][r];
        float mn = fmaxf(mold, mx);
        float a = __expf(mold - mn);
        float rs = 0.f;
        for (int c = 0; c < 4; c++) {
          int col = m0 + c * 16 + l16;
          float pp = (col < seqlen) ? __expf(sf[rb][c][r] * scale - mn) : 0.f;
          pv[r][c] = pp;
          rs += pp;
        }
        for (int off = 1; off < 16; off <<= 1) rs += __shfl_xor(rs, off);
        m_run[rb][r] = mn;
        l_run[rb][r] = l_run[rb][r] * a + rs;
        alpha[r] = a;
      }
      // write P (bf16) to this wave's private Ps rows; rescale O
      for (int r = 0; r < 4; r++) {
        int prow = wid * 32 + rb * 16 + quad * 4 + r;
        for (int c = 0; c < 4; c++) Ps[prow * 72 + c * 16 + l16] = f2bf(pv[r][c]);
      }
      for (int nf = 0; nf < 5; nf++) {
        floatx4 o = of[rb][nf];
        o[0] *= alpha[0]; o[1] *= alpha[1]; o[2] *= alpha[2]; o[3] *= alpha[3];
        of[rb][nf] = o;
      }
    }

    // O += P V  (P via LDS round-trip, same-wave so no barrier needed)
    for (int ks = 0; ks < 2; ks++) {
      bf16x8 pf[2];
      for (int rb = 0; rb < 2; rb++)
        pf[rb] = *(const bf16x8*)(Ps + (wid * 32 + rb * 16 + l16) * 72 + ks * 32 + quad * 8);
      for (int nf = 0; nf < 5; nf++) {
        bf16x8 vf = *(const bf16x8*)(Vs + (nf * 16 + l16) * 72 + ks * 32 + quad * 8);
        for (int rb = 0; rb < 2; rb++)
          of[rb][nf] = __builtin_amdgcn_mfma_f32_16x16x32_bf16(pf[rb], vf, of[rb][nf], 0, 0, 0);
      }
    }
  }

  // normalize + store att [b,n,h*72+d]
  for (int rb = 0; rb < 2; rb++) {
    floatx4 invl;
    for (int r = 0; r < 4; r++) invl[r] = 1.0f / l_run[rb][r];
    for (int nf = 0; nf < 5; nf++) {
      int d = nf * 16 + l16;
      if (d < HDIM) {
        for (int r = 0; r < 4; r++) {
          size_t o = ((size_t)(b * 4096 + n0 + wid * 32 + rb * 16 + quad * 4 + r)) * DIMC +
                     h * HDIM + d;
          att[o] = f2bf(of[rb][nf][r] * invl[r]);
        }
      }
    }
  }
}

// ---------------------------------------------------------------------------
extern "C" void kernel_launch(void* const* d_in, const int* in_sizes, int n_in,
                              void* d_out, int out_size, void* d_ws, size_t ws_size,
                              hipStream_t stream) {
  const float* x      = (const float*)d_in[0];
  const float* cond   = (const float*)d_in[1];
  const int*   seqlen = (const int*)d_in[2];
  const float* q_w    = (const float*)d_in[3];
  const float* q_b    = (const float*)d_in[4];
  const float* kv_w   = (const float*)d_in[5];
  const float* kv_b   = (const float*)d_in[6];
  const float* proj_w = (const float*)d_in[7];
  const float* proj_b = (const float*)d_in[8];
  const float* qn_w   = (const float*)d_in[9];
  const float* kn_w   = (const float*)d_in[10];
  float* out = (float*)d_out;

  char* ws = (char*)d_ws;
  size_t o = 0;
  ushort_t* qwT  = (ushort_t*)(ws + o); o += (size_t)1152 * 1152 * 2;
  ushort_t* kvwT = (ushort_t*)(ws + o); o += (size_t)2304 * 1152 * 2;
  ushort_t* pwT  = (ushort_t*)(ws + o); o += (size_t)1152 * 1152 * 2;
  ushort_t* q16  = (ushort_t*)(ws + o); o += (size_t)16384 * 1152 * 2;
  ushort_t* kv16 = (ushort_t*)(ws + o); o += (size_t)2048 * 2304 * 2;
  ushort_t* vT   = (ushort_t*)(ws + o); o += (size_t)64 * 80 * 512 * 2;
  ushort_t* att  = (ushort_t*)(ws + o); o += (size_t)16384 * 1152 * 2;

  dim3 blk(256);

  // 1) weight convert+transpose to bf16 [N][K]
  transpose_w_kernel<<<dim3(1152 / 64, 1152 / 64), blk, 0, stream>>>(q_w, qwT, 1152, 1152);
  transpose_w_kernel<<<dim3(1152 / 64, 2304 / 64), blk, 0, stream>>>(kv_w, kvwT, 1152, 2304);
  transpose_w_kernel<<<dim3(1152 / 64, 1152 / 64), blk, 0, stream>>>(proj_w, pwT, 1152, 1152);

  // 2) Q = x @ q_w + q_b  (bf16 out)
  gemm_kernel<true, false><<<dim3(1152 / 128, 16384 / 128), blk, 0, stream>>>(
      x, qwT, q_b, q16, 16384, 1152, 1152);
  // 3) KV = cond @ kv_w + kv_b  (bf16 out)
  gemm_kernel<true, false><<<dim3(2304 / 128, 2048 / 128), blk, 0, stream>>>(
      cond, kvwT, kv_b, kv16, 2048, 2304, 1152);

  // 4) RMSNorm q (in place), k (in place, pair-0 cols of kv16)
  rmsnorm_heads_kernel<<<dim3(16384 * 16 / 4), blk, 0, stream>>>(q16, qn_w, 1152);
  rmsnorm_heads_kernel<<<dim3(2048 * 16 / 4), blk, 0, stream>>>(kv16, kn_w, 2304);

  // 5) V -> [b,h,d(80),m] transposed, zero-padded
  vtrans_kernel<<<dim3(64 * 80 / 4), blk, 0, stream>>>(kv16, vT);

  // 6) attention
  attn_kernel<<<dim3(32, 16, 4), blk, 0, stream>>>(q16, kv16, vT, seqlen, att);

  // 7) out = att @ proj_w + proj_b  (fp32 out)
  gemm_kernel<false, true><<<dim3(1152 / 128, 16384 / 128), blk, 0, stream>>>(
      att, pwT, proj_b, out, 16384, 1152, 1152);
}

// Round 3
// 531.547 us; speedup vs baseline: 1.0864x; 1.0864x over previous
//
#include <hip/hip_runtime.h>
#include <math.h>

typedef unsigned short ushort_t;
typedef __attribute__((ext_vector_type(4))) float floatx4;
typedef __attribute__((ext_vector_type(8))) short bf16x8;

#define DIMC 1152
#define NHEADS 16
#define HDIM 72

__device__ __forceinline__ ushort_t f2bf(float f) {
  unsigned u = __float_as_uint(f);
  u += 0x7FFFu + ((u >> 16) & 1u);      // round-to-nearest-even
  return (ushort_t)(u >> 16);
}
__device__ __forceinline__ float bf2f(ushort_t s) {
  return __uint_as_float(((unsigned)s) << 16);
}

__device__ __forceinline__ void gload_lds16(const ushort_t* g, ushort_t* l) {
  __builtin_amdgcn_global_load_lds(
      (const __attribute__((address_space(1))) unsigned int*)(const void*)g,
      (__attribute__((address_space(3))) unsigned int*)(void*)l, 16, 0, 0);
}

// ---------------------------------------------------------------------------
// fp32 -> bf16 elementwise (8 elems/thread)
// ---------------------------------------------------------------------------
__global__ void cvt_bf16_kernel(const float* __restrict__ src,
                                ushort_t* __restrict__ dst, int n8) {
  int i = blockIdx.x * 256 + threadIdx.x;
  if (i >= n8) return;
  float4 f0 = ((const float4*)src)[2 * (size_t)i];
  float4 f1 = ((const float4*)src)[2 * (size_t)i + 1];
  union { ushort_t s[8]; uint4 u; } t;
  t.s[0] = f2bf(f0.x); t.s[1] = f2bf(f0.y); t.s[2] = f2bf(f0.z); t.s[3] = f2bf(f0.w);
  t.s[4] = f2bf(f1.x); t.s[5] = f2bf(f1.y); t.s[6] = f2bf(f1.z); t.s[7] = f2bf(f1.w);
  ((uint4*)dst)[i] = t.u;
}

// ---------------------------------------------------------------------------
// W [K][N] fp32  ->  Wt [N][K] bf16   (64x64 tiles via LDS)
// ---------------------------------------------------------------------------
__global__ void transpose_w_kernel(const float* __restrict__ W,
                                   ushort_t* __restrict__ Wt, int K, int N) {
  __shared__ ushort_t tile[64 * 80];
  int k0 = blockIdx.x * 64, n0 = blockIdx.y * 64;
  int tid = threadIdx.x;
  int kl = tid >> 4, n4 = tid & 15;
  for (int rr = 0; rr < 4; rr++) {
    int k = kl + rr * 16;
    float4 f = *(const float4*)(W + (size_t)(k0 + k) * N + n0 + n4 * 4);
    tile[(n4 * 4 + 0) * 80 + k] = f2bf(f.x);
    tile[(n4 * 4 + 1) * 80 + k] = f2bf(f.y);
    tile[(n4 * 4 + 2) * 80 + k] = f2bf(f.z);
    tile[(n4 * 4 + 3) * 80 + k] = f2bf(f.w);
  }
  __syncthreads();
  int nl = tid >> 2, kq = tid & 3;
  uint4 v0 = *(const uint4*)(tile + nl * 80 + kq * 16);
  uint4 v1 = *(const uint4*)(tile + nl * 80 + kq * 16 + 8);
  *(uint4*)(Wt + (size_t)(n0 + nl) * K + k0 + kq * 16) = v0;
  *(uint4*)(Wt + (size_t)(n0 + nl) * K + k0 + kq * 16 + 8) = v1;
}

// ---------------------------------------------------------------------------
// C[M][N] = A[M][K](bf16) @ Wt[N][K]^T + bias.  C fp32 or bf16.
// 128x128 tile, BK=64, 256 threads (4 waves 2x2, each 64x64 = 4x4 frags).
// LDS in MFMA-fragment chunk order: chunk(cr,cks) = 1024B = [lane][16B],
// written by global_load_lds (wave-uniform base + lane*16), read back as
// ds_read_b128 at base+lane*16 -> conflict-free.
// XCD swizzle: 1-D grid; xcd = lin&7 owns M-stripe, sweeps N fastest.
// ---------------------------------------------------------------------------
template <bool OUT_F32>
__global__ __launch_bounds__(256, 3) void gemm_kernel(
    const ushort_t* __restrict__ A, const ushort_t* __restrict__ Bt,
    const float* __restrict__ bias, void* __restrict__ Cptr,
    int TM, int TN, int Ncols, int Kdim) {
  __shared__ ushort_t As[16 * 512];
  __shared__ ushort_t Bs[16 * 512];
  int lin = blockIdx.x;
  int xcd = lin & 7, slot = lin >> 3;
  int mpx = TM >> 3;
  int mt = xcd * mpx + slot / TN;
  int nt = slot % TN;
  int m0 = mt * 128, n0 = nt * 128;

  int tid = threadIdx.x;
  int wid = tid >> 6, lane = tid & 63, quad = lane >> 4, l16 = lane & 15;
  int wrow = (wid >> 1) * 64, wcol = (wid & 1) * 64;
  int crA = (wid >> 1) * 4;   // first cr this wave reads for A frags
  int crB = (wid & 1) * 4;

  floatx4 zero = {0.f, 0.f, 0.f, 0.f};
  floatx4 acc[4][4];
  for (int i = 0; i < 4; i++)
    for (int j = 0; j < 4; j++) acc[i][j] = zero;

  // per-lane source offsets for this wave's 4 staging chunks (c = wid*4+i)
  // chunk c: cr = c>>1, cks = c&1; row = cr*16 + l16, col = cks*32 + quad*8
  int nK = Kdim >> 6;
  for (int kt = 0; kt < nK; kt++) {
    int k0 = kt * 64;
    __syncthreads();
    for (int i = 0; i < 4; i++) {
      int c = wid * 4 + i;
      int cr = c >> 1, cks = c & 1;
      const ushort_t* ga =
          A + (size_t)(m0 + cr * 16 + l16) * Kdim + k0 + cks * 32 + quad * 8;
      gload_lds16(ga, As + c * 512);
      const ushort_t* gb =
          Bt + (size_t)(n0 + cr * 16 + l16) * Kdim + k0 + cks * 32 + quad * 8;
      gload_lds16(gb, Bs + c * 512);
    }
    __syncthreads();
    for (int ks = 0; ks < 2; ks++) {
      bf16x8 af[4], bfr[4];
      for (int rb = 0; rb < 4; rb++)
        af[rb] = *(const bf16x8*)(As + ((crA + rb) * 2 + ks) * 512 + lane * 8);
      for (int c = 0; c < 4; c++)
        bfr[c] = *(const bf16x8*)(Bs + ((crB + c) * 2 + ks) * 512 + lane * 8);
      for (int rb = 0; rb < 4; rb++)
        for (int c = 0; c < 4; c++)
          acc[rb][c] = __builtin_amdgcn_mfma_f32_16x16x32_bf16(af[rb], bfr[c], acc[rb][c], 0, 0, 0);
    }
  }

  float bv[4];
  for (int c = 0; c < 4; c++) bv[c] = bias[n0 + wcol + c * 16 + l16];
  for (int rb = 0; rb < 4; rb++)
    for (int c = 0; c < 4; c++)
      for (int r = 0; r < 4; r++) {
        int row = m0 + wrow + rb * 16 + quad * 4 + r;
        int col = n0 + wcol + c * 16 + l16;
        float v = acc[rb][c][r] + bv[c];
        if constexpr (OUT_F32)
          ((float*)Cptr)[(size_t)row * Ncols + col] = v;
        else
          ((ushort_t*)Cptr)[(size_t)row * Ncols + col] = f2bf(v);
      }
}

// ---------------------------------------------------------------------------
// In-place per-head RMSNorm on bf16 (one wave per (row, head); 72 elems).
// Used only for K now (Q norm fused into attention).
// ---------------------------------------------------------------------------
__global__ void rmsnorm_heads_kernel(ushort_t* __restrict__ p,
                                     const float* __restrict__ w,
                                     int rowstride) {
  int gw = blockIdx.x * 4 + (threadIdx.x >> 6);
  int lane = threadIdx.x & 63;
  int row = gw >> 4, h = gw & 15;
  ushort_t* base = p + (size_t)row * rowstride + h * HDIM;
  float v0 = bf2f(base[lane]);
  float v1 = (lane < 8) ? bf2f(base[64 + lane]) : 0.f;
  float ss = v0 * v0 + v1 * v1;
  for (int off = 1; off < 64; off <<= 1) ss += __shfl_xor(ss, off);
  float inv = rsqrtf(ss / 72.0f + 1e-6f);
  base[lane] = f2bf(v0 * inv * w[lane]);
  if (lane < 8) base[64 + lane] = f2bf(v1 * inv * w[64 + lane]);
}

// ---------------------------------------------------------------------------
// V [b,m,pair1,h,d] -> vT [b,h,d(80,zero-pad),m(512)]   (one wave per (b,h,d))
// ---------------------------------------------------------------------------
__global__ void vtrans_kernel(const ushort_t* __restrict__ kv16,
                              ushort_t* __restrict__ vT) {
  int gw = blockIdx.x * 4 + (threadIdx.x >> 6);
  int lane = threadIdx.x & 63;
  int d = gw % 80;
  int bh = gw / 80;
  int b = bh >> 4, h = bh & 15;
  ushort_t* dst = vT + (size_t)gw * 512;
  if (d < HDIM) {
    const ushort_t* src = kv16 + (size_t)b * 512 * 2304 + DIMC + h * HDIM + d;
    for (int m = lane; m < 512; m += 64) dst[m] = src[(size_t)m * 2304];
  } else {
    for (int m = lane; m < 512; m += 64) dst[m] = 0;
  }
}

// ---------------------------------------------------------------------------
// Flash cross-attention with fused Q-RMSNorm. Block = (b, h, 128 Q rows).
// ---------------------------------------------------------------------------
__global__ __launch_bounds__(256, 3) void attn_kernel(
    const ushort_t* __restrict__ q16, const ushort_t* __restrict__ kv16,
    const ushort_t* __restrict__ vT, const int* __restrict__ seqlens,
    const float* __restrict__ qn_w, ushort_t* __restrict__ att) {
  __shared__ ushort_t Ks[64 * 104];   // [m 64][d 96, stride 104]
  __shared__ ushort_t Vs[80 * 72];    // [d 80][m 64, stride 72]
  __shared__ ushort_t Ps[128 * 72];   // [qrow 128][m 64, stride 72]
  __shared__ float qnS[HDIM];
  int b = blockIdx.z, h = blockIdx.y, n0 = blockIdx.x * 128;
  int tid = threadIdx.x, wid = tid >> 6, lane = tid & 63;
  int quad = lane >> 4, l16 = lane & 15;
  int seqlen = seqlens[b];
  const float scale = 0.11785113019775793f;  // 1/sqrt(72)

  if (tid < HDIM) qnS[tid] = qn_w[tid];

  // Raw Q fragments (A-operand); k >= 72 zeroed (quad-uniform branch).
  bf16x8 qf[2][3];
  float ssq[2] = {0.f, 0.f};
  for (int rb = 0; rb < 2; rb++)
    for (int ks = 0; ks < 3; ks++) {
      if (ks == 2 && quad > 0) {
        qf[rb][ks] = (bf16x8){0, 0, 0, 0, 0, 0, 0, 0};
      } else {
        size_t off = ((size_t)(b * 4096 + n0 + wid * 32 + rb * 16 + l16)) * DIMC +
                     h * HDIM + ks * 32 + quad * 8;
        union { bf16x8 v; uint2 u[2]; } t;
        t.u[0] = *(const uint2*)(q16 + off);
        t.u[1] = *(const uint2*)(q16 + off + 4);
        qf[rb][ks] = t.v;
        union { bf16x8 v; ushort_t s[8]; } e;
        e.v = t.v;
        for (int j = 0; j < 8; j++) {
          float x = bf2f(e.s[j]);
          ssq[rb] += x * x;
        }
      }
    }
  // reduce ssq across the 4 quads (lanes l16, l16+16, l16+32, l16+48)
  for (int rb = 0; rb < 2; rb++) {
    ssq[rb] += __shfl_xor(ssq[rb], 16);
    ssq[rb] += __shfl_xor(ssq[rb], 32);
  }
  __syncthreads();  // qnS visible
  for (int rb = 0; rb < 2; rb++) {
    float inv = rsqrtf(ssq[rb] / 72.0f + 1e-6f);
    for (int ks = 0; ks < 3; ks++) {
      if (ks == 2 && quad > 0) continue;
      union { bf16x8 v; ushort_t s[8]; } e;
      e.v = qf[rb][ks];
      for (int j = 0; j < 8; j++)
        e.s[j] = f2bf(bf2f(e.s[j]) * inv * qnS[ks * 32 + quad * 8 + j]);
      qf[rb][ks] = e.v;
    }
  }

  floatx4 zero = {0.f, 0.f, 0.f, 0.f};
  floatx4 of[2][5];
  floatx4 m_run[2], l_run[2];
  for (int rb = 0; rb < 2; rb++) {
    for (int nf = 0; nf < 5; nf++) of[rb][nf] = zero;
    m_run[rb] = (floatx4){-INFINITY, -INFINITY, -INFINITY, -INFINITY};
    l_run[rb] = zero;
  }

  int ntiles = (seqlen + 63) >> 6;
  for (int mt = 0; mt < ntiles; mt++) {
    int m0 = mt * 64;
    __syncthreads();
    // stage K tile: 64 rows x 96 cols; each (r,seg) covers 24 bf16 = 3 uint4
    {
      int r = tid >> 2, seg = tid & 3;
      const ushort_t* src = kv16 + ((size_t)(b * 512 + m0 + r)) * 2304 + h * HDIM + seg * 24;
      ushort_t* dst = Ks + r * 104 + seg * 24;
      if (seg < 3) {
        for (int i = 0; i < 3; i++) *(uint4*)(dst + i * 8) = *(const uint4*)(src + i * 8);
      } else {
        uint4 z = make_uint4(0u, 0u, 0u, 0u);
        for (int i = 0; i < 3; i++) *(uint4*)(dst + i * 8) = z;
      }
    }
    // stage V tile
    for (int c = tid; c < 640; c += 256) {
      int d = c >> 3, j = c & 7;
      *(uint4*)(Vs + d * 72 + j * 8) =
          *(const uint4*)(vT + ((size_t)((b * 16 + h) * 80 + d)) * 512 + m0 + j * 8);
    }
    __syncthreads();

    // S = Q K^T
    floatx4 sf[2][4];
    for (int rb = 0; rb < 2; rb++)
      for (int c = 0; c < 4; c++) sf[rb][c] = zero;
    for (int c = 0; c < 4; c++)
      for (int ks = 0; ks < 3; ks++) {
        bf16x8 kf = *(const bf16x8*)(Ks + (c * 16 + l16) * 104 + ks * 32 + quad * 8);
        for (int rb = 0; rb < 2; rb++)
          sf[rb][c] = __builtin_amdgcn_mfma_f32_16x16x32_bf16(qf[rb][ks], kf, sf[rb][c], 0, 0, 0);
      }

    // online softmax per rb (rows quad*4+r; stats reduced over 16 lanes)
    for (int rb = 0; rb < 2; rb++) {
      float pv[4][4], alpha[4];
      for (int r = 0; r < 4; r++) {
        float mx = -INFINITY;
        for (int c = 0; c < 4; c++) {
          int col = m0 + c * 16 + l16;
          float s = sf[rb][c][r] * scale;
          if (col < seqlen && s > mx) mx = s;
        }
        for (int off = 1; off < 16; off <<= 1) {
          float o = __shfl_xor(mx, off);
          if (o > mx) mx = o;
        }
        float mold = m_run[rb][r];
        float mn = fmaxf(mold, mx);
        float a = __expf(mold - mn);
        float rs = 0.f;
        for (int c = 0; c < 4; c++) {
          int col = m0 + c * 16 + l16;
          float pp = (col < seqlen) ? __expf(sf[rb][c][r] * scale - mn) : 0.f;
          pv[r][c] = pp;
          rs += pp;
        }
        for (int off = 1; off < 16; off <<= 1) rs += __shfl_xor(rs, off);
        m_run[rb][r] = mn;
        l_run[rb][r] = l_run[rb][r] * a + rs;
        alpha[r] = a;
      }
      for (int r = 0; r < 4; r++) {
        int prow = wid * 32 + rb * 16 + quad * 4 + r;
        for (int c = 0; c < 4; c++) Ps[prow * 72 + c * 16 + l16] = f2bf(pv[r][c]);
      }
      for (int nf = 0; nf < 5; nf++) {
        floatx4 o = of[rb][nf];
        o[0] *= alpha[0]; o[1] *= alpha[1]; o[2] *= alpha[2]; o[3] *= alpha[3];
        of[rb][nf] = o;
      }
    }

    // O += P V  (P via LDS round-trip, same-wave so no barrier needed)
    for (int ks = 0; ks < 2; ks++) {
      bf16x8 pf[2];
      for (int rb = 0; rb < 2; rb++)
        pf[rb] = *(const bf16x8*)(Ps + (wid * 32 + rb * 16 + l16) * 72 + ks * 32 + quad * 8);
      for (int nf = 0; nf < 5; nf++) {
        bf16x8 vf = *(const bf16x8*)(Vs + (nf * 16 + l16) * 72 + ks * 32 + quad * 8);
        for (int rb = 0; rb < 2; rb++)
          of[rb][nf] = __builtin_amdgcn_mfma_f32_16x16x32_bf16(pf[rb], vf, of[rb][nf], 0, 0, 0);
      }
    }
  }

  // normalize + store att [b,n,h*72+d]
  for (int rb = 0; rb < 2; rb++) {
    floatx4 invl;
    for (int r = 0; r < 4; r++) invl[r] = 1.0f / l_run[rb][r];
    for (int nf = 0; nf < 5; nf++) {
      int d = nf * 16 + l16;
      if (d < HDIM) {
        for (int r = 0; r < 4; r++) {
          size_t o = ((size_t)(b * 4096 + n0 + wid * 32 + rb * 16 + quad * 4 + r)) * DIMC +
                     h * HDIM + d;
          att[o] = f2bf(of[rb][nf][r] * invl[r]);
        }
      }
    }
  }
}

// ---------------------------------------------------------------------------
extern "C" void kernel_launch(void* const* d_in, const int* in_sizes, int n_in,
                              void* d_out, int out_size, void* d_ws, size_t ws_size,
                              hipStream_t stream) {
  const float* x      = (const float*)d_in[0];
  const float* cond   = (const float*)d_in[1];
  const int*   seqlen = (const int*)d_in[2];
  const float* q_w    = (const float*)d_in[3];
  const float* q_b    = (const float*)d_in[4];
  const float* kv_w   = (const float*)d_in[5];
  const float* kv_b   = (const float*)d_in[6];
  const float* proj_w = (const float*)d_in[7];
  const float* proj_b = (const float*)d_in[8];
  const float* qn_w   = (const float*)d_in[9];
  const float* kn_w   = (const float*)d_in[10];
  float* out = (float*)d_out;

  char* ws = (char*)d_ws;
  size_t o = 0;
  ushort_t* qwT    = (ushort_t*)(ws + o); o += (size_t)1152 * 1152 * 2;
  ushort_t* kvwT   = (ushort_t*)(ws + o); o += (size_t)2304 * 1152 * 2;
  ushort_t* pwT    = (ushort_t*)(ws + o); o += (size_t)1152 * 1152 * 2;
  ushort_t* q16    = (ushort_t*)(ws + o); o += (size_t)16384 * 1152 * 2;
  ushort_t* kv16   = (ushort_t*)(ws + o); o += (size_t)2048 * 2304 * 2;
  ushort_t* vT     = (ushort_t*)(ws + o); o += (size_t)64 * 80 * 512 * 2;
  ushort_t* att    = (ushort_t*)(ws + o); o += (size_t)16384 * 1152 * 2;
  ushort_t* x16    = (ushort_t*)(ws + o); o += (size_t)16384 * 1152 * 2;
  ushort_t* cond16 = (ushort_t*)(ws + o); o += (size_t)2048 * 1152 * 2;

  dim3 blk(256);

  // 0) activations fp32 -> bf16
  cvt_bf16_kernel<<<dim3((16384 * 1152 / 8 + 255) / 256), blk, 0, stream>>>(
      x, x16, 16384 * 1152 / 8);
  cvt_bf16_kernel<<<dim3((2048 * 1152 / 8 + 255) / 256), blk, 0, stream>>>(
      cond, cond16, 2048 * 1152 / 8);

  // 1) weight convert+transpose to bf16 [N][K]
  transpose_w_kernel<<<dim3(1152 / 64, 1152 / 64), blk, 0, stream>>>(q_w, qwT, 1152, 1152);
  transpose_w_kernel<<<dim3(1152 / 64, 2304 / 64), blk, 0, stream>>>(kv_w, kvwT, 1152, 2304);
  transpose_w_kernel<<<dim3(1152 / 64, 1152 / 64), blk, 0, stream>>>(proj_w, pwT, 1152, 1152);

  // 2) Q = x @ q_w + q_b  (bf16 out)
  gemm_kernel<false><<<dim3(128 * 9), blk, 0, stream>>>(
      x16, qwT, q_b, q16, 128, 9, 1152, 1152);
  // 3) KV = cond @ kv_w + kv_b  (bf16 out)
  gemm_kernel<false><<<dim3(16 * 18), blk, 0, stream>>>(
      cond16, kvwT, kv_b, kv16, 16, 18, 2304, 1152);

  // 4) RMSNorm k in place (pair-0 cols of kv16); q norm fused into attention
  rmsnorm_heads_kernel<<<dim3(2048 * 16 / 4), blk, 0, stream>>>(kv16, kn_w, 2304);

  // 5) V -> [b,h,d(80),m] transposed, zero-padded
  vtrans_kernel<<<dim3(64 * 80 / 4), blk, 0, stream>>>(kv16, vT);

  // 6) attention (with fused Q-RMSNorm)
  attn_kernel<<<dim3(32, 16, 4), blk, 0, stream>>>(q16, kv16, vT, seqlen, qn_w, att);

  // 7) out = att @ proj_w + proj_b  (fp32 out)
  gemm_kernel<true><<<dim3(128 * 9), blk, 0, stream>>>(
      att, pwT, proj_b, out, 128, 9, 1152, 1152);
}